// Round 14
// baseline (213.234 us; speedup 1.0000x reference)
//
#include <hip/hip_runtime.h>
#include <hip/hip_fp16.h>

typedef _Float16 f16;
typedef _Float16 f16x4 __attribute__((ext_vector_type(4)));
typedef _Float16 f16x8 __attribute__((ext_vector_type(8)));
typedef float f32x4 __attribute__((ext_vector_type(4)));

#define NCH 64          // chunks of 32 rows per batch
#define CHB 32768       // raw bytes per chunk (32 rows x 256 f32)
#define PLB 16384       // plane bytes per chunk (32 rows x 256 f16)
#define PSTRIDE 524288  // psc plane stride (floats) = 256*2048

#define BAR()     asm volatile("s_waitcnt lgkmcnt(0)\n\ts_barrier" ::: "memory")
#define WAITV_(N) asm volatile("s_waitcnt vmcnt(" #N ")" ::: "memory")
#define WAITV(N)  WAITV_(N)

// ---------------------------------------------------------------------------
// prep_w: W[0][d][k] (k<256, feature half) -> fp16 HI plane (RTN), MFMA B-frag
// order [ks(8)][ct(16)][lane(64)][j(8)]: ct=d>>4, lane=(d&15)|(((k>>3)&3)<<4),
// ks=k>>5, j=k&7. Frag (ks,ct) = contiguous 1 KiB.
// ---------------------------------------------------------------------------
__global__ void prep_w(const float* __restrict__ W, f16* __restrict__ wbuf) {
    int idx = blockIdx.x * 256 + threadIdx.x;   // 65536 total
    int d = idx >> 8, k = idx & 255;
    float w = W[d * 512 + k];
    int ct   = d >> 4;
    int lane = (d & 15) | (((k >> 3) & 3) << 4);
    int ks   = k >> 5;
    int j    = k & 7;
    wbuf[(((ks * 16 + ct) * 64) + lane) * 8 + j] = (f16)w;
}

// ---------------------------------------------------------------------------
// prep_c: c[b][d] = sum_e W[0][d][256+e] * h[b][e]   (fp32 exact, tiny)
// ---------------------------------------------------------------------------
__global__ void prep_c(const float* __restrict__ W, const float* __restrict__ h,
                       float* __restrict__ c) {
    __shared__ float hs[256];
    int b = blockIdx.x, d = threadIdx.x;
    hs[d] = h[b * 256 + d];
    __syncthreads();
    const float4* w4 = (const float4*)(W + d * 512 + 256);
    const float4* h4 = (const float4*)hs;
    float acc = 0.f;
#pragma unroll 8
    for (int e = 0; e < 64; ++e) {
        float4 a = w4[e], bb = h4[e];
        acc += a.x * bb.x + a.y * bb.y + a.z * bb.z + a.w * bb.w;
    }
    c[b * 256 + d] = acc;
}

// ---------------------------------------------------------------------------
// main_gemm: single-pass f16, REG-STAGED feature (no raw LDS ring).
// Per chunk t, ONE barrier:
//   BAR -> issue 4x global_load_dwordx4 (chunk t+1 -> st regs) -> MFMA
//   planes[t] (8 ds_read_b128 + 32 MFMA/wave) -> epilogue -> vmcnt(0) ->
//   in-reg cvt st -> ds_write planes[t+1] -> psc store(t).
// Feature path: HBM -> VGPR -> cvt -> LDS(plane) -> VGPR  (one LDS bounce;
// deletes R12's DMA LDS-writes + cvt LDS-reads = half of LDS traffic).
// planes 2x16K f16, XOR-swizzled: elem (row,k) at (row*512+k*2)^((row&7)<<4).
// 8 waves = 2 row-halves x 4 col-groups; wave = 16 rows x 64 cols.
// wf[4][8]=128 VGPR + acc 16 + st 16 -> ~210 regs, 2 waves/SIMD, no spill.
// ---------------------------------------------------------------------------
__global__ __launch_bounds__(512, 2)
void main_gemm(const float* __restrict__ feat, const f16* __restrict__ wbuf,
               const float* __restrict__ cb, const float* __restrict__ vvec,
               float* __restrict__ psc) {
    __shared__ __align__(16) char plnb[2 * PLB];    // 32 KiB f16 planes

    const int tid = threadIdx.x;
    const int w = tid >> 6;       // wave 0..7
    const int l = tid & 63;
    const int g = l >> 4;         // 0..3
    const int lr = l & 15;
    const int rh = w >> 2;        // row-half 0/1
    const int cg = w & 3;         // col-group 0..3 (64 cols each)
    const int b = blockIdx.x;     // batch

    // ---- W-hi fragments for this wave's 64 cols: wf[ct][ks], 128 VGPRs ----
    f16x8 wf[4][8];
    {
        const f16x8* wp = (const f16x8*)wbuf;
#pragma unroll
        for (int ct = 0; ct < 4; ++ct) {
            int ctg = cg * 4 + ct;
#pragma unroll
            for (int ks = 0; ks < 8; ++ks)
                wf[ct][ks] = wp[(ks * 16 + ctg) * 64 + l];
        }
    }
    float c_[4], v_[4];
#pragma unroll
    for (int ct = 0; ct < 4; ++ct) {
        c_[ct] = cb[b * 256 + (cg * 4 + ct) * 16 + lr];
        v_[ct] = vvec[(cg * 4 + ct) * 16 + lr];
    }

    const char* tbb = (const char*)(feat + (size_t)b * 2048 * 256);

    // staging regs: thread tid covers flat elems {r*2048 + tid*4, +4} r=0..3
    f32x4 st[4];
#define LOADC(u)                                                                   \
    {                                                                              \
        const f32x4* sp_ = (const f32x4*)(tbb + (size_t)(u) * CHB + tid * 16);     \
        st[0] = sp_[0];                                                            \
        st[1] = sp_[512];                                                          \
        st[2] = sp_[1024];                                                         \
        st[3] = sp_[1536];                                                         \
    }

    // cvt round r: row = r*8 + w, k0 = (tid&63)*4; plane byte
    // (row*512 + k*2) ^ ((row&7)<<4), f16x4-granular
    const int ck0 = (tid & 63) * 4;
    int cvt_off[4];
#pragma unroll
    for (int r = 0; r < 4; ++r) {
        int row = r * 8 + w;
        cvt_off[r] = (((row * 512 + (ck0 & ~7) * 2) ^ ((row & 7) << 4)) +
                      ((ck0 & 4) << 1));
    }

#define CVTW(u)                                                                    \
    {                                                                              \
        char* hq_ = plnb + ((u) & 1) * PLB;                                        \
        _Pragma("unroll")                                                          \
        for (int r = 0; r < 4; ++r) {                                              \
            f16x4 hv_ = {(f16)st[r][0], (f16)st[r][1], (f16)st[r][2], (f16)st[r][3]}; \
            *(f16x4*)(hq_ + cvt_off[r]) = hv_;                                     \
        }                                                                          \
    }

    // MFMA-phase A addressing (constant per lane): row = rh*16+lr
    const int arow = rh * 16 + lr;
    const int aswz = (arow & 7) << 4;

    // ---- prologue: load chunk 0, cvt into planes[0] ----
    LOADC(0);
    WAITV(0);
    CVTW(0);

    for (int t = 0; t < NCH; ++t) {
        BAR();           // planes[t] visible; plane slot (t+1)&1 free
        if (t + 1 < NCH) LOADC(t + 1);   // issue early; retire after epilogue

        const char* hp = plnb + (t & 1) * PLB;
        f32x4 acc[4] = {};
#pragma unroll
        for (int ks = 0; ks < 8; ++ks) {
            int ao = (arow * 512 + ks * 64 + g * 16) ^ aswz;
            f16x8 ahi = *(const f16x8*)(hp + ao);
            acc[0] = __builtin_amdgcn_mfma_f32_16x16x32_f16(ahi, wf[0][ks], acc[0], 0, 0, 0);
            acc[1] = __builtin_amdgcn_mfma_f32_16x16x32_f16(ahi, wf[1][ks], acc[1], 0, 0, 0);
            acc[2] = __builtin_amdgcn_mfma_f32_16x16x32_f16(ahi, wf[2][ks], acc[2], 0, 0, 0);
            acc[3] = __builtin_amdgcn_mfma_f32_16x16x32_f16(ahi, wf[3][ks], acc[3], 0, 0, 0);
        }

        // ---- epilogue: +c, tanh, *v, reduce over 64 cols ----
        // acc[ct][r]: row = rh*16 + g*4 + r, col = (cg*4+ct)*16 + lr
        float s[4];
#pragma unroll
        for (int r = 0; r < 4; ++r) {
            float a = 0.f;
#pragma unroll
            for (int ct = 0; ct < 4; ++ct) {
                float x = acc[ct][r] + c_[ct];
                float tnh = 1.f - __fdividef(2.f, __expf(2.f * x) + 1.f);
                a += v_[ct] * tnh;
            }
            s[r] = a;
        }
#pragma unroll
        for (int m = 1; m < 16; m <<= 1) {
            s[0] += __shfl_xor(s[0], m, 64);
            s[1] += __shfl_xor(s[1], m, 64);
            s[2] += __shfl_xor(s[2], m, 64);
            s[3] += __shfl_xor(s[3], m, 64);
        }

        // ---- retire loads (issued ~3000 cyc ago), cvt, write planes[t+1] ---
        if (t + 1 < NCH) {
            WAITV(0);
            CVTW(t + 1);
        }

        if (lr == 0) {
            size_t rowg = (size_t)b * 2048 + (size_t)t * 32 + rh * 16 + g * 4;
            float4 o = {s[0], s[1], s[2], s[3]};
            *(float4*)(psc + (size_t)cg * PSTRIDE + rowg) = o;
        }
    }
#undef LOADC
#undef CVTW
}

// ---------------------------------------------------------------------------
// softmax over n (2048) per b, summing 4 plane partials per row.
// ---------------------------------------------------------------------------
__global__ void softmax_k(const float* __restrict__ psc, float* __restrict__ out) {
    __shared__ float red[16];
    int b = blockIdx.x, tid = threadIdx.x;  // 256 threads
    float sc[8];
    float m = -3.4e38f;
#pragma unroll
    for (int q = 0; q < 8; ++q) {
        size_t row = (size_t)b * 2048 + q * 256 + tid;
        sc[q] = (psc[row] + psc[PSTRIDE + row]) +
                (psc[2 * PSTRIDE + row] + psc[3 * PSTRIDE + row]);
        m = fmaxf(m, sc[q]);
    }
#pragma unroll
    for (int d = 1; d < 64; d <<= 1) m = fmaxf(m, __shfl_xor(m, d, 64));
    if ((tid & 63) == 0) red[tid >> 6] = m;
    __syncthreads();
    m = fmaxf(fmaxf(red[0], red[1]), fmaxf(red[2], red[3]));
    float e[8], sum = 0.f;
#pragma unroll
    for (int q = 0; q < 8; ++q) { e[q] = __expf(sc[q] - m); sum += e[q]; }
#pragma unroll
    for (int d = 1; d < 64; d <<= 1) sum += __shfl_xor(sum, d, 64);
    if ((tid & 63) == 0) red[8 + (tid >> 6)] = sum;
    __syncthreads();
    sum = (red[8] + red[9]) + (red[10] + red[11]);
    float inv = __fdividef(1.f, sum);
#pragma unroll
    for (int q = 0; q < 8; ++q)
        out[(size_t)b * 2048 + q * 256 + tid] = e[q] * inv;
}

// ---------------------------------------------------------------------------
extern "C" void kernel_launch(void* const* d_in, const int* in_sizes, int n_in,
                              void* d_out, int out_size, void* d_ws, size_t ws_size,
                              hipStream_t stream) {
    const float* feat = (const float*)d_in[0];   // [256,2048,256]
    const float* h    = (const float*)d_in[1];   // [256,256]
    const float* v    = (const float*)d_in[2];   // [256]
    const float* W    = (const float*)d_in[3];   // [256,512]
    float* out = (float*)d_out;                  // [256,1,2048]

    f16*   wbuf = (f16*)d_ws;                         // 131072 B (hi plane)
    float* cbuf = (float*)((char*)d_ws + 131072);     // 262144 B
    float* psc  = (float*)((char*)d_ws + 524288);     // 4 planes x 2 MiB

    prep_w<<<256, 256, 0, stream>>>(W, wbuf);
    prep_c<<<256, 256, 0, stream>>>(W, h, cbuf);
    main_gemm<<<256, 512, 0, stream>>>(feat, wbuf, cbuf, v, psc);
    softmax_k<<<256, 256, 0, stream>>>(psc, out);
}

// Round 15
// 178.133 us; speedup vs baseline: 1.1970x; 1.1970x over previous
//
#include <hip/hip_runtime.h>
#include <hip/hip_fp16.h>

typedef _Float16 f16;
typedef _Float16 f16x4 __attribute__((ext_vector_type(4)));
typedef _Float16 f16x8 __attribute__((ext_vector_type(8)));
typedef float f32x4 __attribute__((ext_vector_type(4)));

#define NCH 64          // chunks of 32 rows per batch
#define CHB 32768       // raw bytes per chunk (32 rows x 256 f32)
#define PLB 16384       // plane bytes per chunk (32 rows x 256 f16)
#define PSTRIDE 524288  // psc plane stride (floats) = 256*2048

#define BAR()     asm volatile("s_waitcnt lgkmcnt(0)\n\ts_barrier" ::: "memory")
#define WAITV_(N) asm volatile("s_waitcnt vmcnt(" #N ")" ::: "memory")
#define WAITV(N)  WAITV_(N)

// ---------------------------------------------------------------------------
// prep_w: W[0][d][k] (k<256, feature half) -> fp16 HI plane (RTN), MFMA B-frag
// order [ks(8)][ct(16)][lane(64)][j(8)]: ct=d>>4, lane=(d&15)|(((k>>3)&3)<<4),
// ks=k>>5, j=k&7. Frag (ks,ct) = contiguous 1 KiB.
// ---------------------------------------------------------------------------
__global__ void prep_w(const float* __restrict__ W, f16* __restrict__ wbuf) {
    int idx = blockIdx.x * 256 + threadIdx.x;   // 65536 total
    int d = idx >> 8, k = idx & 255;
    float w = W[d * 512 + k];
    int ct   = d >> 4;
    int lane = (d & 15) | (((k >> 3) & 3) << 4);
    int ks   = k >> 5;
    int j    = k & 7;
    wbuf[(((ks * 16 + ct) * 64) + lane) * 8 + j] = (f16)w;
}

// ---------------------------------------------------------------------------
// prep_c: c[b][d] = sum_e W[0][d][256+e] * h[b][e]   (fp32 exact, tiny)
// ---------------------------------------------------------------------------
__global__ void prep_c(const float* __restrict__ W, const float* __restrict__ h,
                       float* __restrict__ c) {
    __shared__ float hs[256];
    int b = blockIdx.x, d = threadIdx.x;
    hs[d] = h[b * 256 + d];
    __syncthreads();
    const float4* w4 = (const float4*)(W + d * 512 + 256);
    const float4* h4 = (const float4*)hs;
    float acc = 0.f;
#pragma unroll 8
    for (int e = 0; e < 64; ++e) {
        float4 a = w4[e], bb = h4[e];
        acc += a.x * bb.x + a.y * bb.y + a.z * bb.z + a.w * bb.w;
    }
    c[b * 256 + d] = acc;
}

// ---------------------------------------------------------------------------
// main_gemm: R12 structure at 4 WAVES/SIMD. 256 blocks x 1024 threads
// (16 waves = 2 row-halves x 8 col-groups; wave = 16 rows x 32 cols).
// wf[2][8]=64 VGPR + acc[2]=8 -> ~110 regs: the 1024-thread block forces
// the compiler to fit 4 waves/SIMD (vs R12's 2) -> 2x latency hiding for
// the unchanged pipeline:
//   BAR -> ISSUE(t+2) [2x global_load_lds] -> MFMA planes[t] (8 ds_read +
//   16 MFMA/wave) -> epilogue -> WAITV(2) -> coop-CVT(t+1) -> psc store(t).
// raw ring 2x32K linear fp32 DMA; planes 2x16K f16 XOR-swizzled
// ((row*512+k*2)^((row&7)<<4)); single-pass f16 (absmax 0.0078 measured).
// ---------------------------------------------------------------------------
__global__ __launch_bounds__(1024)
void main_gemm(const float* __restrict__ feat, const f16* __restrict__ wbuf,
               const float* __restrict__ cb, const float* __restrict__ vvec,
               float* __restrict__ psc) {
    __shared__ __align__(16) char rawb[2 * CHB];    // 64 KiB fp32 ring
    __shared__ __align__(16) char plnb[2 * PLB];    // 32 KiB f16 planes

    const int tid = threadIdx.x;
    const int w = tid >> 6;       // wave 0..15
    const int l = tid & 63;
    const int g = l >> 4;         // 0..3
    const int lr = l & 15;
    const int rh = w & 1;         // row-half 0/1
    const int cg = w >> 1;        // col-group 0..7 (32 cols each)
    const int b = blockIdx.x;     // batch

    // ---- W-hi fragments for this wave's 32 cols: wf[ct][ks], 64 VGPRs ----
    f16x8 wf[2][8];
    {
        const f16x8* wp = (const f16x8*)wbuf;
#pragma unroll
        for (int ct = 0; ct < 2; ++ct) {
            int ctg = cg * 2 + ct;
#pragma unroll
            for (int ks = 0; ks < 8; ++ks)
                wf[ct][ks] = wp[(ks * 16 + ctg) * 64 + l];
        }
    }
    float c_[2], v_[2];
#pragma unroll
    for (int ct = 0; ct < 2; ++ct) {
        c_[ct] = cb[b * 256 + (cg * 2 + ct) * 16 + lr];
        v_[ct] = vvec[(cg * 2 + ct) * 16 + lr];
    }

    const char* tbb = (const char*)(feat + (size_t)b * 2048 * 256);

    // DMA: 2 rounds x 1024 thr x 16 B = 32 KB, fully linear both sides.
#define ISSUE(u)                                                                   \
    {                                                                              \
        const char* nb_ = tbb + (size_t)(u) * CHB;                                 \
        char* Q_ = rawb + ((u) & 1) * CHB;                                         \
        _Pragma("unroll")                                                          \
        for (int i_ = 0; i_ < 2; ++i_)                                             \
            __builtin_amdgcn_global_load_lds(                                      \
                (const __attribute__((address_space(1))) void*)(nb_ + i_ * 16384 + tid * 16), \
                (__attribute__((address_space(3))) void*)(Q_ + i_ * 16384 + tid * 16),\
                16, 0, 0);                                                         \
    }

    // cvt round r (r=0..1): flat elems r*4096 + tid*4 -> row = r*16 + (tid>>6),
    // k0 = (tid&63)*4; plane byte (row*512+k*2)^((row&7)<<4), f16x4-granular.
    const int ck0 = (tid & 63) * 4;
    int cvt_off[2];
#pragma unroll
    for (int r = 0; r < 2; ++r) {
        int row = r * 16 + (tid >> 6);
        cvt_off[r] = (((row * 512 + (ck0 & ~7) * 2) ^ ((row & 7) << 4)) +
                      ((ck0 & 4) << 1));
    }

#define CVT(u)                                                                     \
    {                                                                              \
        const char* rp_ = rawb + ((u) & 1) * CHB;                                  \
        char* hq_ = plnb + ((u) & 1) * PLB;                                        \
        _Pragma("unroll")                                                          \
        for (int r = 0; r < 2; ++r) {                                              \
            f32x4 x_ = *(const f32x4*)(rp_ + r * 16384 + tid * 16);                \
            f16x4 hv_ = {(f16)x_[0], (f16)x_[1], (f16)x_[2], (f16)x_[3]};          \
            *(f16x4*)(hq_ + cvt_off[r]) = hv_;                                     \
        }                                                                          \
    }

    // MFMA-phase A addressing (constant per lane): row = rh*16+lr
    const int arow = rh * 16 + lr;
    const int aswz = (arow & 7) << 4;

    // ---- prologue: DMA chunks 0,1; cvt chunk 0 ----
    ISSUE(0); ISSUE(1);
    WAITV(2);            // raw[0] complete (raw[1]'s 2 still flying)
    CVT(0);

    for (int t = 0; t < NCH; ++t) {
        BAR();           // planes[t] visible; raw slot (t&1) free for DMA
        if (t + 2 < NCH) ISSUE(t + 2);

        const char* hp = plnb + (t & 1) * PLB;
        f32x4 acc[2] = {};
#pragma unroll
        for (int ks = 0; ks < 8; ++ks) {
            int ao = (arow * 512 + ks * 64 + g * 16) ^ aswz;
            f16x8 ahi = *(const f16x8*)(hp + ao);
            acc[0] = __builtin_amdgcn_mfma_f32_16x16x32_f16(ahi, wf[0][ks], acc[0], 0, 0, 0);
            acc[1] = __builtin_amdgcn_mfma_f32_16x16x32_f16(ahi, wf[1][ks], acc[1], 0, 0, 0);
        }

        // ---- epilogue: +c, tanh, *v, reduce over 32 cols ----
        // acc[ct][r]: row = rh*16 + g*4 + r, col = (cg*2+ct)*16 + lr
        float s[4];
#pragma unroll
        for (int r = 0; r < 4; ++r) {
            float x0 = acc[0][r] + c_[0];
            float x1 = acc[1][r] + c_[1];
            float t0 = 1.f - __fdividef(2.f, __expf(2.f * x0) + 1.f);
            float t1 = 1.f - __fdividef(2.f, __expf(2.f * x1) + 1.f);
            s[r] = v_[0] * t0 + v_[1] * t1;
        }
#pragma unroll
        for (int m = 1; m < 16; m <<= 1) {
            s[0] += __shfl_xor(s[0], m, 64);
            s[1] += __shfl_xor(s[1], m, 64);
            s[2] += __shfl_xor(s[2], m, 64);
            s[3] += __shfl_xor(s[3], m, 64);
        }

        // ---- retire raw[t+1] (2 loads + prev store), cvt it ----
        if (t < NCH - 2)      WAITV(2);
        else if (t == NCH - 2) WAITV(0);
        if (t + 1 < NCH) CVT(t + 1);

        if (lr == 0) {
            size_t rowg = (size_t)b * 2048 + (size_t)t * 32 + rh * 16 + g * 4;
            float4 o = {s[0], s[1], s[2], s[3]};
            *(float4*)(psc + (size_t)cg * PSTRIDE + rowg) = o;
        }
    }
#undef ISSUE
#undef CVT
}

// ---------------------------------------------------------------------------
// softmax over n (2048) per b, summing 8 plane partials per row.
// ---------------------------------------------------------------------------
__global__ void softmax_k(const float* __restrict__ psc, float* __restrict__ out) {
    __shared__ float red[16];
    int b = blockIdx.x, tid = threadIdx.x;  // 256 threads
    float sc[8];
    float m = -3.4e38f;
#pragma unroll
    for (int q = 0; q < 8; ++q) {
        size_t row = (size_t)b * 2048 + q * 256 + tid;
        float a0 = psc[row] + psc[PSTRIDE + row];
        float a1 = psc[2 * PSTRIDE + row] + psc[3 * PSTRIDE + row];
        float a2 = psc[4 * PSTRIDE + row] + psc[5 * PSTRIDE + row];
        float a3 = psc[6 * PSTRIDE + row] + psc[7 * PSTRIDE + row];
        sc[q] = (a0 + a1) + (a2 + a3);
        m = fmaxf(m, sc[q]);
    }
#pragma unroll
    for (int d = 1; d < 64; d <<= 1) m = fmaxf(m, __shfl_xor(m, d, 64));
    if ((tid & 63) == 0) red[tid >> 6] = m;
    __syncthreads();
    m = fmaxf(fmaxf(red[0], red[1]), fmaxf(red[2], red[3]));
    float e[8], sum = 0.f;
#pragma unroll
    for (int q = 0; q < 8; ++q) { e[q] = __expf(sc[q] - m); sum += e[q]; }
#pragma unroll
    for (int d = 1; d < 64; d <<= 1) sum += __shfl_xor(sum, d, 64);
    if ((tid & 63) == 0) red[8 + (tid >> 6)] = sum;
    __syncthreads();
    sum = (red[8] + red[9]) + (red[10] + red[11]);
    float inv = __fdividef(1.f, sum);
#pragma unroll
    for (int q = 0; q < 8; ++q)
        out[(size_t)b * 2048 + q * 256 + tid] = e[q] * inv;
}

// ---------------------------------------------------------------------------
extern "C" void kernel_launch(void* const* d_in, const int* in_sizes, int n_in,
                              void* d_out, int out_size, void* d_ws, size_t ws_size,
                              hipStream_t stream) {
    const float* feat = (const float*)d_in[0];   // [256,2048,256]
    const float* h    = (const float*)d_in[1];   // [256,256]
    const float* v    = (const float*)d_in[2];   // [256]
    const float* W    = (const float*)d_in[3];   // [256,512]
    float* out = (float*)d_out;                  // [256,1,2048]

    f16*   wbuf = (f16*)d_ws;                         // 131072 B (hi plane)
    float* cbuf = (float*)((char*)d_ws + 131072);     // 262144 B
    float* psc  = (float*)((char*)d_ws + 524288);     // 8 planes x 2 MiB

    prep_w<<<256, 256, 0, stream>>>(W, wbuf);
    prep_c<<<256, 256, 0, stream>>>(W, h, cbuf);
    main_gemm<<<256, 1024, 0, stream>>>(feat, wbuf, cbuf, v, psc);
    softmax_k<<<256, 256, 0, stream>>>(psc, out);
}

// Round 16
// 172.773 us; speedup vs baseline: 1.2342x; 1.0310x over previous
//
#include <hip/hip_runtime.h>
#include <hip/hip_fp16.h>

typedef _Float16 f16;
typedef _Float16 f16x4 __attribute__((ext_vector_type(4)));
typedef _Float16 f16x8 __attribute__((ext_vector_type(8)));
typedef float f32x4 __attribute__((ext_vector_type(4)));

#define NCH 64          // chunks of 32 rows per batch
#define CHB 32768       // raw bytes per chunk (32 rows x 256 f32)
#define PLB 16384       // plane bytes per chunk (32 rows x 256 f16)

#define BAR()     asm volatile("s_waitcnt lgkmcnt(0)\n\ts_barrier" ::: "memory")
#define WAITV_(N) asm volatile("s_waitcnt vmcnt(" #N ")" ::: "memory")
#define WAITV(N)  WAITV_(N)

// ---------------------------------------------------------------------------
// fused: everything in one kernel. 256 blocks (block b == batch b) x 512 thr.
// Prologue (per block): stage h[b] -> LDS; c[d] = W2[d,:].h[b] in-block ->
// cl[256]; W1 frags loaded DIRECTLY from W + cvt f16 into wf[4][8] (same
// lane mapping as the old prep_w: d=(cg*4+ct)*16+lr, k=ks*32+g*8+j).
// Main loop: EXACT R12 structure (best measured: single-pass f16, coop-cvt,
// DMA ring 2x32K depth-2, counted vmcnt, planes 2x16K XOR-swizzled).
//   BAR -> ISSUE(t+2) -> 8x{ds_read_b128 + 4 MFMA} -> epilogue(+c,tanh,*v,
//   16-lane shfl reduce) -> WAITV(4) -> coop-CVT(t+1) -> pbuf partials.
// Scores: pbuf[2][32][4] LDS partials; rotating wave finalizes chunk t-1
// into sbuf[2048] after the barrier. Tail: in-block softmax over sbuf,
// write out[b*2048..] directly. No psc, no extra kernels, d_ws unused.
// ---------------------------------------------------------------------------
__global__ __launch_bounds__(512, 2)
void fused(const float* __restrict__ feat, const float* __restrict__ hvec,
           const float* __restrict__ vvec, const float* __restrict__ W,
           float* __restrict__ out) {
    __shared__ __align__(16) char rawb[2 * CHB];    // 64 KiB fp32 ring
    __shared__ __align__(16) char plnb[2 * PLB];    // 32 KiB f16 planes
    __shared__ __align__(16) float pbuf[2][32][4];  // per-chunk partials
    __shared__ __align__(16) float sbuf[2048];      // scores for this batch
    __shared__ __align__(16) float hs[256];         // h[b]
    __shared__ __align__(16) float cl[256];         // c[b][d]
    __shared__ float red[16];

    const int tid = threadIdx.x;
    const int w = tid >> 6;       // wave 0..7
    const int l = tid & 63;
    const int g = l >> 4;         // 0..3
    const int lr = l & 15;
    const int rh = w >> 2;        // row-half 0/1
    const int cg = w & 3;         // col-group 0..3 (64 cols each)
    const int b = blockIdx.x;     // batch

    // ---- stage h[b] ----
    if (tid < 256) hs[tid] = hvec[b * 256 + tid];
    __syncthreads();

    // ---- c[d] = sum_e W[d][256+e]*h[b][e]: 2 threads per d ----
    {
        int d = tid >> 1, half = tid & 1;
        const float4* w4 = (const float4*)(W + d * 512 + 256 + half * 128);
        const float4* h4 = (const float4*)(hs + half * 128);
        float a = 0.f;
#pragma unroll 8
        for (int e = 0; e < 32; ++e) {
            float4 x = w4[e], y = h4[e];
            a += x.x * y.x + x.y * y.y + x.z * y.z + x.w * y.w;
        }
        a += __shfl_xor(a, 1, 64);
        if (half == 0) cl[d] = a;
    }

    // ---- W1 frags direct from W (f32 load + RTN cvt), 128 VGPRs ----
    f16x8 wf[4][8];
#pragma unroll
    for (int ct = 0; ct < 4; ++ct) {
        int d = (cg * 4 + ct) * 16 + lr;
        const float* wr = W + d * 512 + g * 8;
#pragma unroll
        for (int ks = 0; ks < 8; ++ks) {
            float4 a0 = *(const float4*)(wr + ks * 32);
            float4 a1 = *(const float4*)(wr + ks * 32 + 4);
            f16x8 hv = {(f16)a0.x, (f16)a0.y, (f16)a0.z, (f16)a0.w,
                        (f16)a1.x, (f16)a1.y, (f16)a1.z, (f16)a1.w};
            wf[ct][ks] = hv;
        }
    }
    float v_[4];
#pragma unroll
    for (int ct = 0; ct < 4; ++ct) v_[ct] = vvec[(cg * 4 + ct) * 16 + lr];
    __syncthreads();              // cl ready
    float c_[4];
#pragma unroll
    for (int ct = 0; ct < 4; ++ct) c_[ct] = cl[(cg * 4 + ct) * 16 + lr];

    const char* tbb = (const char*)(feat + (size_t)b * 2048 * 256);

#define ISSUE(u)                                                                   \
    {                                                                              \
        const char* nb_ = tbb + (size_t)(u) * CHB;                                 \
        char* Q_ = rawb + ((u) & 1) * CHB;                                         \
        _Pragma("unroll")                                                          \
        for (int i_ = 0; i_ < 4; ++i_)                                             \
            __builtin_amdgcn_global_load_lds(                                      \
                (const __attribute__((address_space(1))) void*)(nb_ + i_ * 8192 + tid * 16), \
                (__attribute__((address_space(3))) void*)(Q_ + i_ * 8192 + tid * 16),\
                16, 0, 0);                                                         \
    }

    // cvt round r: flat elems r*2048 + tid*4 -> row r*8+w, k0=(tid&63)*4
    const int ck0 = (tid & 63) * 4;
    int cvt_off[4];
#pragma unroll
    for (int r = 0; r < 4; ++r) {
        int row = r * 8 + w;
        cvt_off[r] = (((row * 512 + (ck0 & ~7) * 2) ^ ((row & 7) << 4)) +
                      ((ck0 & 4) << 1));
    }

#define CVT(u)                                                                     \
    {                                                                              \
        const char* rp_ = rawb + ((u) & 1) * CHB;                                  \
        char* hq_ = plnb + ((u) & 1) * PLB;                                        \
        _Pragma("unroll")                                                          \
        for (int r = 0; r < 4; ++r) {                                              \
            f32x4 x_ = *(const f32x4*)(rp_ + r * 8192 + tid * 16);                 \
            f16x4 hv_ = {(f16)x_[0], (f16)x_[1], (f16)x_[2], (f16)x_[3]};          \
            *(f16x4*)(hq_ + cvt_off[r]) = hv_;                                     \
        }                                                                          \
    }

    // MFMA-phase A addressing (constant per lane): row = rh*16+lr
    const int arow = rh * 16 + lr;
    const int aswz = (arow & 7) << 4;

    // ---- prologue: DMA chunks 0,1; cvt chunk 0 ----
    ISSUE(0); ISSUE(1);
    WAITV(4);            // raw[0] done (raw[1]'s 4 may remain; prologue loads drain too)
    CVT(0);

    for (int t = 0; t < NCH; ++t) {
        BAR();           // planes[t] + pbuf(t-1) visible; raw slot (t&1) free
        if (t + 2 < NCH) ISSUE(t + 2);

        // rotating wave finalizes chunk t-1's score partials into sbuf
        if (t > 0 && w == ((t - 1) & 7) && l < 32) {
            const float* pb_ = &pbuf[(t - 1) & 1][l][0];
            f32x4 p_ = *(const f32x4*)pb_;
            sbuf[(t - 1) * 32 + l] = (p_[0] + p_[1]) + (p_[2] + p_[3]);
        }

        const char* hp = plnb + (t & 1) * PLB;
        f32x4 acc[4] = {};
#pragma unroll
        for (int ks = 0; ks < 8; ++ks) {
            int ao = (arow * 512 + ks * 64 + g * 16) ^ aswz;
            f16x8 ahi = *(const f16x8*)(hp + ao);
            acc[0] = __builtin_amdgcn_mfma_f32_16x16x32_f16(ahi, wf[0][ks], acc[0], 0, 0, 0);
            acc[1] = __builtin_amdgcn_mfma_f32_16x16x32_f16(ahi, wf[1][ks], acc[1], 0, 0, 0);
            acc[2] = __builtin_amdgcn_mfma_f32_16x16x32_f16(ahi, wf[2][ks], acc[2], 0, 0, 0);
            acc[3] = __builtin_amdgcn_mfma_f32_16x16x32_f16(ahi, wf[3][ks], acc[3], 0, 0, 0);
        }

        // ---- epilogue: +c, tanh, *v, reduce over 64 cols ----
        float s[4];
#pragma unroll
        for (int r = 0; r < 4; ++r) {
            float a = 0.f;
#pragma unroll
            for (int ct = 0; ct < 4; ++ct) {
                float x = acc[ct][r] + c_[ct];
                float tnh = 1.f - __fdividef(2.f, __expf(2.f * x) + 1.f);
                a += v_[ct] * tnh;
            }
            s[r] = a;
        }
#pragma unroll
        for (int m = 1; m < 16; m <<= 1) {
            s[0] += __shfl_xor(s[0], m, 64);
            s[1] += __shfl_xor(s[1], m, 64);
            s[2] += __shfl_xor(s[2], m, 64);
            s[3] += __shfl_xor(s[3], m, 64);
        }

        // ---- retire raw[t+1] loads, cvt them (raw[t+2] stays in flight) ----
        if (t < NCH - 2)      WAITV(4);
        else if (t == NCH - 2) WAITV(0);
        if (t + 1 < NCH) CVT(t + 1);

        // ---- partials to LDS pbuf (finalized next chunk) ----
        if (lr == 0) {
            int r0 = rh * 16 + g * 4;
            pbuf[t & 1][r0 + 0][cg] = s[0];
            pbuf[t & 1][r0 + 1][cg] = s[1];
            pbuf[t & 1][r0 + 2][cg] = s[2];
            pbuf[t & 1][r0 + 3][cg] = s[3];
        }
    }
#undef ISSUE
#undef CVT

    // ---- finalize last chunk's partials ----
    BAR();
    if (w == ((NCH - 1) & 7) && l < 32) {
        const float* pb_ = &pbuf[(NCH - 1) & 1][l][0];
        f32x4 p_ = *(const f32x4*)pb_;
        sbuf[(NCH - 1) * 32 + l] = (p_[0] + p_[1]) + (p_[2] + p_[3]);
    }
    BAR();

    // ---- in-block softmax over sbuf[2048], write out ----
    {
        f32x4 x = *(const f32x4*)(sbuf + tid * 4);
        float m = fmaxf(fmaxf(x[0], x[1]), fmaxf(x[2], x[3]));
#pragma unroll
        for (int d = 1; d < 64; d <<= 1) m = fmaxf(m, __shfl_xor(m, d, 64));
        if (l == 0) red[w] = m;
        __syncthreads();
        m = fmaxf(fmaxf(fmaxf(red[0], red[1]), fmaxf(red[2], red[3])),
                  fmaxf(fmaxf(red[4], red[5]), fmaxf(red[6], red[7])));
        float e0 = __expf(x[0] - m), e1 = __expf(x[1] - m);
        float e2 = __expf(x[2] - m), e3 = __expf(x[3] - m);
        float sum = (e0 + e1) + (e2 + e3);
#pragma unroll
        for (int d = 1; d < 64; d <<= 1) sum += __shfl_xor(sum, d, 64);
        if (l == 0) red[8 + w] = sum;
        __syncthreads();
        sum = ((red[8] + red[9]) + (red[10] + red[11])) +
              ((red[12] + red[13]) + (red[14] + red[15]));
        float inv = __fdividef(1.f, sum);
        float4 o = {e0 * inv, e1 * inv, e2 * inv, e3 * inv};
        *(float4*)(out + (size_t)b * 2048 + tid * 4) = o;
    }
}

// ---------------------------------------------------------------------------
extern "C" void kernel_launch(void* const* d_in, const int* in_sizes, int n_in,
                              void* d_out, int out_size, void* d_ws, size_t ws_size,
                              hipStream_t stream) {
    const float* feat = (const float*)d_in[0];   // [256,2048,256]
    const float* h    = (const float*)d_in[1];   // [256,256]
    const float* v    = (const float*)d_in[2];   // [256]
    const float* W    = (const float*)d_in[3];   // [256,512]
    float* out = (float*)d_out;                  // [256,1,2048]

    fused<<<256, 512, 0, stream>>>(feat, h, v, W, out);
}

// Round 17
// 167.681 us; speedup vs baseline: 1.2717x; 1.0304x over previous
//
#include <hip/hip_runtime.h>
#include <hip/hip_fp16.h>

typedef _Float16 f16;
typedef _Float16 f16x4 __attribute__((ext_vector_type(4)));
typedef _Float16 f16x8 __attribute__((ext_vector_type(8)));
typedef float f32x4 __attribute__((ext_vector_type(4)));

#define NCH 64          // chunks of 32 rows per batch
#define CHB 32768       // raw bytes per chunk (32 rows x 256 f32)
#define PLB 16384       // plane bytes per chunk (32 rows x 256 f16)
#define PSTRIDE 524288  // psc plane stride (floats) = 256*2048

#define BAR()     asm volatile("s_waitcnt lgkmcnt(0)\n\ts_barrier" ::: "memory")
#define WAITV_(N) asm volatile("s_waitcnt vmcnt(" #N ")" ::: "memory")
#define WAITV(N)  WAITV_(N)

// ---------------------------------------------------------------------------
// prep_w: W[0][d][k] (k<256, feature half) -> fp16 HI plane (RTN), MFMA B-frag
// order [ks(8)][ct(16)][lane(64)][j(8)]: ct=d>>4, lane=(d&15)|(((k>>3)&3)<<4),
// ks=k>>5, j=k&7. Frag (ks,ct) = contiguous 1 KiB.
// ---------------------------------------------------------------------------
__global__ void prep_w(const float* __restrict__ W, f16* __restrict__ wbuf) {
    int idx = blockIdx.x * 256 + threadIdx.x;   // 65536 total
    int d = idx >> 8, k = idx & 255;
    float w = W[d * 512 + k];
    int ct   = d >> 4;
    int lane = (d & 15) | (((k >> 3) & 3) << 4);
    int ks   = k >> 5;
    int j    = k & 7;
    wbuf[(((ks * 16 + ct) * 64) + lane) * 8 + j] = (f16)w;
}

// ---------------------------------------------------------------------------
// prep_c: c[b][d] = sum_e W[0][d][256+e] * h[b][e]   (fp32 exact, tiny)
// ---------------------------------------------------------------------------
__global__ void prep_c(const float* __restrict__ W, const float* __restrict__ h,
                       float* __restrict__ c) {
    __shared__ float hs[256];
    int b = blockIdx.x, d = threadIdx.x;
    hs[d] = h[b * 256 + d];
    __syncthreads();
    const float4* w4 = (const float4*)(W + d * 512 + 256);
    const float4* h4 = (const float4*)hs;
    float acc = 0.f;
#pragma unroll 8
    for (int e = 0; e < 64; ++e) {
        float4 a = w4[e], bb = h4[e];
        acc += a.x * bb.x + a.y * bb.y + a.z * bb.z + a.w * bb.w;
    }
    c[b * 256 + d] = acc;
}

// ---------------------------------------------------------------------------
// main_gemm: SINGLE-PASS f16 (f_hi*W_hi, RTN conversions; dropped terms
// f_lo*W + f_hi*W_lo each ~2^-12-scale; measured absmax 0.0078).
// Best-measured structure (R12): raw ring 2x32K (linear fp32 DMA), planes
// 2x16K f16 hi only, XOR-swizzled: elem (row,k) at (row*512+k*2)^((row&7)<<4).
// Per iter t: BAR -> ISSUE(t+2) -> MFMA planes[t] (8 ds_read + 32 MFMA/wave)
// -> epilogue -> WAITV(4) -> CVT(t+1) -> psc store. vmcnt never 0 in steady.
// 8 waves = 2 row-halves x 4 col-groups; wave = 16 rows x 64 cols.
// wf[4][8]=128 VGPR + acc 16 -> ~190 regs, 2 waves/SIMD, no spill.
// ---------------------------------------------------------------------------
__global__ __launch_bounds__(512, 2)
void main_gemm(const float* __restrict__ feat, const f16* __restrict__ wbuf,
               const float* __restrict__ cb, const float* __restrict__ vvec,
               float* __restrict__ psc) {
    __shared__ __align__(16) char rawb[2 * CHB];    // 64 KiB fp32 ring
    __shared__ __align__(16) char plnb[2 * PLB];    // 32 KiB f16 hi planes

    const int tid = threadIdx.x;
    const int w = tid >> 6;       // wave 0..7
    const int l = tid & 63;
    const int g = l >> 4;         // 0..3
    const int lr = l & 15;
    const int rh = w >> 2;        // row-half 0/1
    const int cg = w & 3;         // col-group 0..3 (64 cols each)
    const int b = blockIdx.x;     // batch

    // ---- W-hi fragments for this wave's 64 cols: wf[ct][ks], 128 VGPRs ----
    f16x8 wf[4][8];
    {
        const f16x8* wp = (const f16x8*)wbuf;
#pragma unroll
        for (int ct = 0; ct < 4; ++ct) {
            int ctg = cg * 4 + ct;
#pragma unroll
            for (int ks = 0; ks < 8; ++ks)
                wf[ct][ks] = wp[(ks * 16 + ctg) * 64 + l];
        }
    }
    float c_[4], v_[4];
#pragma unroll
    for (int ct = 0; ct < 4; ++ct) {
        c_[ct] = cb[b * 256 + (cg * 4 + ct) * 16 + lr];
        v_[ct] = vvec[(cg * 4 + ct) * 16 + lr];
    }

    const char* tbb = (const char*)(feat + (size_t)b * 2048 * 256);

    // DMA: 4 rounds x 512 thr x 16 B = 32 KB, fully linear both sides.
#define ISSUE(u)                                                                   \
    {                                                                              \
        const char* nb = tbb + (size_t)(u) * CHB;                                  \
        char* Q = rawb + ((u) & 1) * CHB;                                          \
        _Pragma("unroll")                                                          \
        for (int i = 0; i < 4; ++i)                                                \
            __builtin_amdgcn_global_load_lds(                                      \
                (const __attribute__((address_space(1))) void*)(nb + i * 8192 + tid * 16), \
                (__attribute__((address_space(3))) void*)(Q + i * 8192 + tid * 16),\
                16, 0, 0);                                                         \
    }

    // cvt round r: flat elems r*2048 + tid*4 -> row r*8+w, k0=(tid&63)*4
    const int ck0 = (tid & 63) * 4;
    int cvt_off[4];
#pragma unroll
    for (int r = 0; r < 4; ++r) {
        int row = r * 8 + w;
        cvt_off[r] = (((row * 512 + (ck0 & ~7) * 2) ^ ((row & 7) << 4)) +
                      ((ck0 & 4) << 1));
    }

#define CVT(u)                                                                     \
    {                                                                              \
        const char* rp = rawb + ((u) & 1) * CHB;                                   \
        char* hq = plnb + ((u) & 1) * PLB;                                         \
        _Pragma("unroll")                                                          \
        for (int r = 0; r < 4; ++r) {                                              \
            f32x4 x = *(const f32x4*)(rp + r * 8192 + tid * 16);                   \
            f16x4 hv = {(f16)x[0], (f16)x[1], (f16)x[2], (f16)x[3]};               \
            *(f16x4*)(hq + cvt_off[r]) = hv;                                       \
        }                                                                          \
    }

    // MFMA-phase A addressing (constant per lane): row = rh*16+lr
    const int arow = rh * 16 + lr;
    const int aswz = (arow & 7) << 4;

    // ---- prologue: DMA chunks 0,1; cvt chunk 0 ----
    ISSUE(0); ISSUE(1);
    WAITV(4);            // raw[0] complete (raw[1] still flying)
    CVT(0);

    for (int t = 0; t < NCH; ++t) {
        BAR();           // planes[t] visible; raw slot (t&1) free for DMA
        if (t + 2 < NCH) ISSUE(t + 2);

        const char* hp = plnb + (t & 1) * PLB;
        f32x4 acc[4] = {};
#pragma unroll
        for (int ks = 0; ks < 8; ++ks) {
            int ao = (arow * 512 + ks * 64 + g * 16) ^ aswz;
            f16x8 ahi = *(const f16x8*)(hp + ao);
            acc[0] = __builtin_amdgcn_mfma_f32_16x16x32_f16(ahi, wf[0][ks], acc[0], 0, 0, 0);
            acc[1] = __builtin_amdgcn_mfma_f32_16x16x32_f16(ahi, wf[1][ks], acc[1], 0, 0, 0);
            acc[2] = __builtin_amdgcn_mfma_f32_16x16x32_f16(ahi, wf[2][ks], acc[2], 0, 0, 0);
            acc[3] = __builtin_amdgcn_mfma_f32_16x16x32_f16(ahi, wf[3][ks], acc[3], 0, 0, 0);
        }

        // ---- epilogue compute: +c, tanh, *v, reduce over 64 cols ----
        // acc[ct][r]: row = rh*16 + g*4 + r, col = (cg*4+ct)*16 + lr
        float s[4];
#pragma unroll
        for (int r = 0; r < 4; ++r) {
            float a = 0.f;
#pragma unroll
            for (int ct = 0; ct < 4; ++ct) {
                float x = acc[ct][r] + c_[ct];
                float tnh = 1.f - __fdividef(2.f, __expf(2.f * x) + 1.f);
                a += v_[ct] * tnh;
            }
            s[r] = a;
        }
#pragma unroll
        for (int m = 1; m < 16; m <<= 1) {
            s[0] += __shfl_xor(s[0], m, 64);
            s[1] += __shfl_xor(s[1], m, 64);
            s[2] += __shfl_xor(s[2], m, 64);
            s[3] += __shfl_xor(s[3], m, 64);
        }

        // ---- retire raw[t+1], cvt it (raw[t+2] stays in flight) ----
        if (t < NCH - 2)      WAITV(4);
        else if (t == NCH - 2) WAITV(0);
        if (t + 1 < NCH) CVT(t + 1);

        if (lr == 0) {
            size_t rowg = (size_t)b * 2048 + t * 32 + rh * 16 + g * 4;
            float4 o = {s[0], s[1], s[2], s[3]};
            *(float4*)(psc + (size_t)cg * PSTRIDE + rowg) = o;
        }
    }
#undef ISSUE
#undef CVT
}

// ---------------------------------------------------------------------------
// softmax over n (2048) per b, summing 4 plane partials per row.
// ---------------------------------------------------------------------------
__global__ void softmax_k(const float* __restrict__ psc, float* __restrict__ out) {
    __shared__ float red[16];
    int b = blockIdx.x, tid = threadIdx.x;  // 256 threads
    float sc[8];
    float m = -3.4e38f;
#pragma unroll
    for (int q = 0; q < 8; ++q) {
        size_t row = (size_t)b * 2048 + q * 256 + tid;
        sc[q] = (psc[row] + psc[PSTRIDE + row]) +
                (psc[2 * PSTRIDE + row] + psc[3 * PSTRIDE + row]);
        m = fmaxf(m, sc[q]);
    }
#pragma unroll
    for (int d = 1; d < 64; d <<= 1) m = fmaxf(m, __shfl_xor(m, d, 64));
    if ((tid & 63) == 0) red[tid >> 6] = m;
    __syncthreads();
    m = fmaxf(fmaxf(red[0], red[1]), fmaxf(red[2], red[3]));
    float e[8], sum = 0.f;
#pragma unroll
    for (int q = 0; q < 8; ++q) { e[q] = __expf(sc[q] - m); sum += e[q]; }
#pragma unroll
    for (int d = 1; d < 64; d <<= 1) sum += __shfl_xor(sum, d, 64);
    if ((tid & 63) == 0) red[8 + (tid >> 6)] = sum;
    __syncthreads();
    sum = (red[8] + red[9]) + (red[10] + red[11]);
    float inv = __fdividef(1.f, sum);
#pragma unroll
    for (int q = 0; q < 8; ++q)
        out[(size_t)b * 2048 + q * 256 + tid] = e[q] * inv;
}

// ---------------------------------------------------------------------------
extern "C" void kernel_launch(void* const* d_in, const int* in_sizes, int n_in,
                              void* d_out, int out_size, void* d_ws, size_t ws_size,
                              hipStream_t stream) {
    const float* feat = (const float*)d_in[0];   // [256,2048,256]
    const float* h    = (const float*)d_in[1];   // [256,256]
    const float* v    = (const float*)d_in[2];   // [256]
    const float* W    = (const float*)d_in[3];   // [256,512]
    float* out = (float*)d_out;                  // [256,1,2048]

    f16*   wbuf = (f16*)d_ws;                         // 131072 B (hi plane)
    float* cbuf = (float*)((char*)d_ws + 131072);     // 262144 B
    float* psc  = (float*)((char*)d_ws + 524288);     // 4 planes x 2 MiB

    prep_w<<<256, 256, 0, stream>>>(W, wbuf);
    prep_c<<<256, 256, 0, stream>>>(W, h, cbuf);
    main_gemm<<<256, 512, 0, stream>>>(feat, wbuf, cbuf, v, psc);
    softmax_k<<<256, 256, 0, stream>>>(psc, out);
}